// Round 1
// baseline (187.989 us; speedup 1.0000x reference)
//
#include <hip/hip_runtime.h>
#include <hip/hip_bf16.h>

typedef __attribute__((ext_vector_type(8))) short bf16x8;
typedef __attribute__((ext_vector_type(4))) float f32x4;

#define TAIL 32           // contraction ~e^-1.5/step: worst-of-16K truncation err ~3e-10
#define TSTART (2048 - TAIL)

static __device__ __forceinline__ ushort f2bf(float f) {
    union { float f; uint u; } v; v.f = f;
    uint u = v.u;
    return (ushort)((u + 0x7FFFu + ((u >> 16) & 1u)) >> 16);
}
static __device__ __forceinline__ float softsign_f(float x) {
    return x / (1.0f + fabsf(x));
}

// One block per (b, 32-u slice): g>>3 = b, (g&7)*32 = u0.  512 blocks x 256 thr.
// Phases: stage X-tail + W_i slice to LDS (bf16, k-chunked), float4 dot partials ->
// barrier -> dot reduce + MFMA GEMM (each wave: one 16t x 16u quadrant) ->
// S[u][t] f32 in LDS -> barrier -> 32-thread register scan + epilogue.
__global__ __launch_bounds__(256, 2) void fused_pid(
    const float* __restrict__ U, const float* __restrict__ X,
    const float* __restrict__ R_z, const float* __restrict__ b_z,
    const float* __restrict__ R_b, const float* __restrict__ W_p,
    const float* __restrict__ W_i, const float* __restrict__ W_d,
    float* __restrict__ out)
{
    __shared__ ushort sA[32][32][8];   // X tail bf16: (tl,k) -> [k>>3][tl][k&7]
    __shared__ ushort sB[32][33][8];   // W_i slice : (k,n)  -> [k>>3][n][k&7], n<32
    __shared__ float  S[32][36];       // GEMM result S[u][t], padded stride
    __shared__ float  pd[6][32][36];   // dot partials [which][kq][u], pad 36 (16B-aligned, 4-bank kq stride)
    __shared__ float  dot6[6][32];     // reduced dots

    const int tid  = threadIdx.x;
    const int g    = blockIdx.x;
    const int b    = g >> 3;
    const int u0   = (g & 7) * 32;
    const int lane = tid & 63, wv = tid >> 6;
    const int quad = lane >> 4, l16 = lane & 15;

    // ---- stage X tail: 32 x 256 f32 -> bf16 k-chunked ----
    {
        const float* Xb = X + ((size_t)b * 2048 + TSTART) * 256;
#pragma unroll
        for (int s = 0; s < 8; ++s) {
            int c = s * 256 + tid;
            int tl = c >> 6, ch = c & 63;              // ch = float4 index in row
            float4 f = *(const float4*)(Xb + tl * 256 + ch * 4);
            ushort4 h;
            h.x = f2bf(f.x); h.y = f2bf(f.y); h.z = f2bf(f.z); h.w = f2bf(f.w);
            *(ushort4*)&sA[ch >> 1][tl][(ch & 1) * 4] = h;
        }
    }
    // ---- stage W_i slice: 256 x 32 f32 -> bf16 k-chunked ----
    {
        int n = tid & 31, kg = tid >> 5;               // kg in 0..7
#pragma unroll
        for (int gi = 0; gi < 4; ++gi) {
            int k8 = kg * 32 + gi * 8;
            ushort tmp[8];
#pragma unroll
            for (int j = 0; j < 8; ++j)
                tmp[j] = f2bf(W_i[(size_t)(k8 + j) * 256 + u0 + n]);
            *(int4*)&sB[k8 >> 3][n][0] = *(int4*)tmp;
        }
    }
    // ---- dot partials: 6 dots x 32 u, float4 along u; thread = (u4-grp, k-octet) ----
    {
        const int ug = tid & 7;                        // u4 group: u = ug*4 .. +3
        const int kq = tid >> 3;                       // 0..31, 8 k each
        const int ub = u0 + ug * 4;
        const float* Ub = U + b * 256;
        const float* xl = X + ((size_t)b * 2048 + 2047) * 256;
        const float* xp = xl - 256;
        float aU[4] = {0.f,0.f,0.f,0.f}, aP[4] = {0.f,0.f,0.f,0.f}, aD[4] = {0.f,0.f,0.f,0.f};
        float aZ0[4] = {0.f,0.f,0.f,0.f}, aZ1[4] = {0.f,0.f,0.f,0.f}, aZ2[4] = {0.f,0.f,0.f,0.f};
#pragma unroll
        for (int j = 0; j < 8; ++j) {
            int k = kq * 8 + j;
            float uk  = Ub[k];                         // broadcast across 8 ug lanes
            float xlk = xl[k];
            float dxk = xlk - xp[k];
            float4 rb = *(const float4*)&R_b[k * 256 + ub];
            float4 wp = *(const float4*)&W_p[k * 256 + ub];
            float4 wd = *(const float4*)&W_d[k * 256 + ub];
            const float* rz = &R_z[k * 768 + ub * 3];  // 12 floats = (u,c) for 4 u x 3 c
            float4 z0 = *(const float4*)&rz[0];
            float4 z1 = *(const float4*)&rz[4];
            float4 z2 = *(const float4*)&rz[8];
            aU[0] += uk * rb.x; aU[1] += uk * rb.y; aU[2] += uk * rb.z; aU[3] += uk * rb.w;
            aP[0] += xlk * wp.x; aP[1] += xlk * wp.y; aP[2] += xlk * wp.z; aP[3] += xlk * wp.w;
            aD[0] += dxk * wd.x; aD[1] += dxk * wd.y; aD[2] += dxk * wd.z; aD[3] += dxk * wd.w;
            // element e of [z0|z1|z2]: u = e/3, c = e%3
            aZ0[0] += uk * z0.x; aZ1[0] += uk * z0.y; aZ2[0] += uk * z0.z;
            aZ0[1] += uk * z0.w; aZ1[1] += uk * z1.x; aZ2[1] += uk * z1.y;
            aZ0[2] += uk * z1.z; aZ1[2] += uk * z1.w; aZ2[2] += uk * z2.x;
            aZ0[3] += uk * z2.y; aZ1[3] += uk * z2.z; aZ2[3] += uk * z2.w;
        }
        f32x4 t;
        t = (f32x4){aU[0],  aU[1],  aU[2],  aU[3]};  *(f32x4*)&pd[0][kq][ug * 4] = t;
        t = (f32x4){aZ0[0], aZ0[1], aZ0[2], aZ0[3]}; *(f32x4*)&pd[1][kq][ug * 4] = t;
        t = (f32x4){aZ1[0], aZ1[1], aZ1[2], aZ1[3]}; *(f32x4*)&pd[2][kq][ug * 4] = t;
        t = (f32x4){aZ2[0], aZ2[1], aZ2[2], aZ2[3]}; *(f32x4*)&pd[3][kq][ug * 4] = t;
        t = (f32x4){aP[0],  aP[1],  aP[2],  aP[3]};  *(f32x4*)&pd[4][kq][ug * 4] = t;
        t = (f32x4){aD[0],  aD[1],  aD[2],  aD[3]};  *(f32x4*)&pd[5][kq][ug * 4] = t;
    }
    __syncthreads();

    // ---- reduce dots (192 threads) ----
    if (tid < 192) {
        int wh = tid >> 5, u = tid & 31;
        float s = 0.f;
#pragma unroll
        for (int j = 0; j < 32; ++j) s += pd[wh][j][u];
        if (wh >= 1 && wh <= 3) s += b_z[(u0 + u) * 3 + (wh - 1)];
        dot6[wh][u] = s;
    }

    // ---- GEMM: 32t x 32u x 256k; wave wv owns quadrant (t-half wv>>1, u-half wv&1) ----
    {
        const int tb  = (wv >> 1) * 16;
        const int ub2 = (wv & 1) * 16;
        f32x4 acc = {0.f, 0.f, 0.f, 0.f};
#pragma unroll
        for (int ks = 0; ks < 8; ++ks) {
            bf16x8 af = *(bf16x8*)&sA[ks * 4 + quad][tb + l16][0];
            bf16x8 bf = *(bf16x8*)&sB[ks * 4 + quad][ub2 + l16][0];
            acc = __builtin_amdgcn_mfma_f32_16x16x32_bf16(af, bf, acc, 0, 0, 0);
        }
        // C/D: row(t) = quad*4+reg, col(u) = l16 -> transposed store S[u][t], b128
        *(f32x4*)&S[ub2 + l16][tb + quad * 4] = acc;
    }
    __syncthreads();

    // ---- scan (threads 0..31, one u each) + epilogue ----
    if (tid < 32) {
        float v[32];
#pragma unroll
        for (int j = 0; j < 8; ++j)
            *(f32x4*)&v[j * 4] = *(const f32x4*)&S[tid][j * 4];
        float p = 0.f, q = 1.f;            // I = p/q, I_{TSTART-1} ~= 0
#pragma unroll
        for (int t = 0; t < 32; ++t) {
            p = fmaf(v[t], q, p);          // p' = p + a*q
            q = q + fabsf(p);              // q' = q + |p'|
            if ((t & 15) == 15) {          // renorm: q stays well inside f32 range
                float r = 1.0f / q;
                p *= r; q = 1.0f;
            }
        }
        float I = p;                       // q == 1 after final renorm
        float P = softsign_f(dot6[0][tid] + dot6[4][tid]);
        float D = softsign_f(dot6[5][tid]);
        out[b * 256 + u0 + tid] = dot6[1][tid] * P + dot6[2][tid] * I + dot6[3][tid] * D;
    }
}

extern "C" void kernel_launch(void* const* d_in, const int* in_sizes, int n_in,
                              void* d_out, int out_size, void* d_ws, size_t ws_size,
                              hipStream_t stream) {
    const float* U   = (const float*)d_in[0];
    const float* X   = (const float*)d_in[1];
    const float* R_z = (const float*)d_in[2];
    const float* b_z = (const float*)d_in[3];
    const float* R_b = (const float*)d_in[6];
    const float* W_p = (const float*)d_in[7];
    const float* W_i = (const float*)d_in[8];
    const float* W_d = (const float*)d_in[9];

    hipLaunchKernelGGL(fused_pid, dim3(512), dim3(256), 0, stream,
                       U, X, R_z, b_z, R_b, W_p, W_i, W_d, (float*)d_out);
}